// Round 4
// baseline (107.192 us; speedup 1.0000x reference)
//
#include <hip/hip_runtime.h>
#include <math.h>

// Problem constants (fixed by setup_inputs): N_ref=128, N_src=128, D=256.
#define NREF 128
#define NSRC 128
#define DIM  256
#define EPS  1e-5f

// ---------------------------------------------------------------------------
// K1 (129 blocks x 512):
//  blocks 0..127: feat_score row i = ref_feats[i] . src_feats[j] for all j,
//    PLUS per-row max/argmax (ascending j + strict > == jnp first-occurrence).
//  block 128: point pipeline (transform src, centroid, max-norm, normalize)
//    -> stages px/py/pz/nsq to ws (runs concurrently with feat rows).
// ---------------------------------------------------------------------------
__global__ __launch_bounds__(512) void feat_kernel(
    const float* __restrict__ ref_feats,
    const float* __restrict__ src_feats,
    const float* __restrict__ points_c,
    const float* __restrict__ trans,
    float* __restrict__ feat_mat,
    float* __restrict__ rowF, int* __restrict__ rowFi,
    float* __restrict__ pts_ws)   // [px 256 | py 256 | pz 256 | nsq 256]
{
    __shared__ __align__(16) float refrow[DIM];
    __shared__ float wmv[8];  __shared__ int wmi[8];
    __shared__ float wred[16], red[4];

    const int t = threadIdx.x;
    const int w = t >> 6, l = t & 63;

    if (blockIdx.x == 128) {
        // ---- points block (threads 0..255 active) ----
        float x = 0.f, y = 0.f, z = 0.f;
        if (t < 256) {
            x = points_c[3 * t + 0];
            y = points_c[3 * t + 1];
            z = points_c[3 * t + 2];
            if (t >= NREF) {
                float nx = trans[0] * x + trans[1] * y + trans[2]  * z + trans[3];
                float ny = trans[4] * x + trans[5] * y + trans[6]  * z + trans[7];
                float nz = trans[8] * x + trans[9] * y + trans[10] * z + trans[11];
                x = nx; y = ny; z = nz;
            }
            float sx = x, sy = y, sz = z;
            for (int off = 32; off >= 1; off >>= 1) {
                sx += __shfl_down(sx, off);
                sy += __shfl_down(sy, off);
                sz += __shfl_down(sz, off);
            }
            if (l == 0) {
                wred[w] = sx; wred[4 + w] = sy; wred[8 + w] = sz;
            }
        }
        __syncthreads();
        if (t == 0) {
            red[0] = (wred[0] + wred[1] + wred[2] + wred[3]) * (1.0f / 256.0f);
            red[1] = (wred[4] + wred[5] + wred[6] + wred[7]) * (1.0f / 256.0f);
            red[2] = (wred[8] + wred[9] + wred[10] + wred[11]) * (1.0f / 256.0f);
        }
        __syncthreads();
        if (t < 256) {
            x -= red[0]; y -= red[1]; z -= red[2];
            float n = x * x + y * y + z * z;
            float mx = n;
            for (int off = 32; off >= 1; off >>= 1)
                mx = fmaxf(mx, __shfl_down(mx, off));
            if (l == 0) wred[w] = mx;
        }
        __syncthreads();
        if (t == 0)
            red[3] = 1.0f / sqrtf(fmaxf(fmaxf(wred[0], wred[1]), fmaxf(wred[2], wred[3])));
        __syncthreads();
        if (t < 256) {
            const float inv = red[3];
            x *= inv; y *= inv; z *= inv;
            pts_ws[t]       = x;
            pts_ws[256 + t] = y;
            pts_ws[512 + t] = z;
            pts_ws[768 + t] = x * x + y * y + z * z;
        }
        return;
    }

    // ---- feat row block ----
    const int i = blockIdx.x;
    if (t < 64) ((float4*)refrow)[t] = ((const float4*)(ref_feats + i * DIM))[t];
    __syncthreads();

    const float4 r = ((const float4*)refrow)[l];
    float bv = -2.f; int bi = 0;

    for (int m = 0; m < 16; m += 2) {
        const int j0 = w * 16 + m;
        const int j1 = j0 + 1;
        const float4 a0 = ((const float4*)(src_feats + j0 * DIM))[l];
        const float4 a1 = ((const float4*)(src_feats + j1 * DIM))[l];
        float acc0 = a0.x * r.x + a0.y * r.y + a0.z * r.z + a0.w * r.w;
        float acc1 = a1.x * r.x + a1.y * r.y + a1.z * r.z + a1.w * r.w;
        for (int off = 32; off >= 1; off >>= 1) {
            acc0 += __shfl_down(acc0, off);
            acc1 += __shfl_down(acc1, off);
        }
        if (l == 0) {
            feat_mat[i * NSRC + j0] = acc0;
            feat_mat[i * NSRC + j1] = acc1;
            if (acc0 > bv) { bv = acc0; bi = j0; }   // ascending j, strict >
            if (acc1 > bv) { bv = acc1; bi = j1; }
        }
    }
    if (l == 0) { wmv[w] = bv; wmi[w] = bi; }
    __syncthreads();
    if (t == 0) {
        float fv = -2.f; int fi = 0;
        for (int ww = 0; ww < 8; ++ww)            // ascending wave == ascending j
            if (wmv[ww] > fv) { fv = wmv[ww]; fi = wmi[ww]; }
        rowF[i] = fv; rowFi[i] = fi;
    }
}

// ---------------------------------------------------------------------------
// K2 (1 x 1024): dist row/col argmax (LDS points, recomputed, ONE shared
// d(i,j) expression -> bitwise-identical row vs col), feat COL argmax
// (coalesced global reads), gathers, stable ranks -> geo[512].
// ---------------------------------------------------------------------------
__global__ __launch_bounds__(1024) void geo_kernel(
    const float* __restrict__ pts_ws,
    const float* __restrict__ feat_mat,
    const float* __restrict__ rowF, const int* __restrict__ rowFi,
    float* __restrict__ geo_out)
{
    __shared__ float px[256], py[256], pz[256], nsq[256];
    __shared__ float pvD[1024]; __shared__ int piD[1024];
    __shared__ float pvF[512];  __shared__ int piF[512];
    __shared__ float min_dist[256];   __shared__ int match_idx[256];
    __shared__ float match_feat[256]; __shared__ int feat_idx[256];
    __shared__ float feat_score[256], match_dist[256];
    __shared__ int prD[1024]; __shared__ int prF[1024];

    const int t = threadIdx.x;
    if (t < 256) {
        px[t]  = pts_ws[t];
        py[t]  = pts_ws[256 + t];
        pz[t]  = pts_ws[512 + t];
        nsq[t] = pts_ws[768 + t];
    }
    __syncthreads();

    // ---- P2: chunked scans ----
    {
        const int rc = t & 255, q = t >> 8;
        if (rc < 128) {
            const int i = rc;
            float bdv = -1.f; int bdi = 0;
            for (int m = 0; m < 32; ++m) {
                const int j = q * 32 + m;
                float d = nsq[i] + nsq[128 + j]
                        - 2.0f * (px[i] * px[128 + j] + py[i] * py[128 + j] + pz[i] * pz[128 + j]);
                d = fmaxf(d, 0.f);
                const float v = expf(-d);
                if (v > bdv) { bdv = v; bdi = j; }
            }
            pvD[q * 256 + rc] = bdv; piD[q * 256 + rc] = bdi;
        } else {
            const int j = rc - 128;
            float bdv = -1.f; int bdi = 0;
            float bfv = -2.f; int bfi = 0;
            for (int m = 0; m < 32; ++m) {
                const int i = q * 32 + m;
                float d = nsq[i] + nsq[128 + j]
                        - 2.0f * (px[i] * px[128 + j] + py[i] * py[128 + j] + pz[i] * pz[128 + j]);
                d = fmaxf(d, 0.f);
                const float v = expf(-d);
                if (v > bdv) { bdv = v; bdi = i; }
                const float f = feat_mat[i * NSRC + j];   // lanes j-adjacent: coalesced
                if (f > bfv) { bfv = f; bfi = i; }
            }
            pvD[q * 256 + rc] = bdv; piD[q * 256 + rc] = bdi;
            pvF[q * 128 + j]  = bfv; piF[q * 128 + j]  = bfi;
        }
    }
    __syncthreads();

    // ---- P3: combine chunks (ascending q + strict > == first occurrence) ----
    if (t < 256) {
        float bv = -1.f; int bi = 0;
        for (int q = 0; q < 4; ++q) {
            const float v = pvD[q * 256 + t];
            if (v > bv) { bv = v; bi = piD[q * 256 + t]; }
        }
        min_dist[t] = bv; match_idx[t] = bi;
        if (t < 128) {
            match_feat[t] = rowF[t]; feat_idx[t] = rowFi[t];
        } else {
            const int j = t - 128;
            float fv = -2.f; int fi = 0;
            for (int q = 0; q < 4; ++q) {
                const float v = pvF[q * 128 + j];
                if (v > fv) { fv = v; fi = piF[q * 128 + j]; }
            }
            match_feat[t] = fv; feat_idx[t] = fi;
        }
    }
    __syncthreads();

    // ---- P4: gathers ----
    if (t < 256) {
        if (t < NREF) {
            const int i = t;
            feat_score[t] = feat_mat[i * NSRC + match_idx[t]];
            const int j = feat_idx[t];
            float d = nsq[i] + nsq[128 + j]
                    - 2.0f * (px[i] * px[128 + j] + py[i] * py[128 + j] + pz[i] * pz[128 + j]);
            d = fmaxf(d, 0.f);
            match_dist[t] = expf(-d);
        } else {
            const int j = t - 128;
            feat_score[t] = feat_mat[match_idx[t] * NSRC + j];
            const int i = feat_idx[t];
            float d = nsq[i] + nsq[128 + j]
                    - 2.0f * (px[i] * px[128 + j] + py[i] * py[128 + j] + pz[i] * pz[128 + j]);
            d = fmaxf(d, 0.f);
            match_dist[t] = expf(-d);
        }
    }
    __syncthreads();

    // ---- P5: stable descending ranks (== jnp.argsort(-v)), chunked 4x64 ----
    {
        const int e = t & 255, q = t >> 8;
        const float v  = min_dist[e];
        const float wv = match_feat[e];
        int r1 = 0, r2 = 0;
        for (int m = 0; m < 64; ++m) {
            const int j = q * 64 + m;
            const float u  = min_dist[j];
            r1 += (u > v) || (u == v && j < e);
            const float uf = match_feat[j];
            r2 += (uf > wv) || (uf == wv && j < e);
        }
        prD[q * 256 + e] = r1;
        prF[q * 256 + e] = r2;
    }
    __syncthreads();
    if (t < 256) {
        const int r  = prD[t] + prD[256 + t] + prD[512 + t] + prD[768 + t];
        geo_out[r] = min_dist[t] * feat_score[t];
        const int rf = prF[t] + prF[256 + t] + prF[512 + t] + prF[768 + t];
        geo_out[256 + rf] = match_dist[t] * match_feat[t];
    }
}

// ---------------------------------------------------------------------------
// K3: y1[c] = geo . W1[c,:] + b1[c]. 256 blocks x 64: W1 streamed chip-wide.
// ---------------------------------------------------------------------------
__global__ __launch_bounds__(64) void mlp1_kernel(
    const float* __restrict__ geo,
    const float* __restrict__ W1, const float* __restrict__ b1,
    float* __restrict__ y1)
{
    const int c = blockIdx.x, l = threadIdx.x;
    const float4 ga = ((const float4*)geo)[l];
    const float4 gb = ((const float4*)geo)[64 + l];
    const float4* __restrict__ wrow = (const float4*)(W1 + c * 512);
    const float4 a = wrow[l];
    const float4 b = wrow[64 + l];
    float acc = a.x * ga.x + a.y * ga.y + a.z * ga.z + a.w * ga.w
              + b.x * gb.x + b.y * gb.y + b.z * gb.z + b.w * gb.w;
    acc += __shfl_down(acc, 32);
    acc += __shfl_down(acc, 16);
    acc += __shfl_down(acc, 8);
    acc += __shfl_down(acc, 4);
    acc += __shfl_down(acc, 2);
    acc += __shfl_down(acc, 1);
    if (l == 0) y1[c] = acc + b1[c];
}

// ---------------------------------------------------------------------------
// K4: h1 = relu(GN8(y1)*g1+bt1); y2[c] = h1 . W2[c,:] + b2[c]. 128 x 64.
// ---------------------------------------------------------------------------
__global__ __launch_bounds__(64) void mlp2_kernel(
    const float* __restrict__ y1,
    const float* __restrict__ g1, const float* __restrict__ bt1,
    const float* __restrict__ W2, const float* __restrict__ b2,
    float* __restrict__ y2)
{
    __shared__ __align__(16) float y1s[256];
    __shared__ float stats[16];
    const int c = blockIdx.x, l = threadIdx.x;
    ((float4*)y1s)[l] = ((const float4*)y1)[l];
    __syncthreads();
    if (l < 8) {
        float s = 0.f;
        for (int k = 0; k < 32; ++k) s += y1s[(l << 5) + k];
        const float mean = s * (1.0f / 32.0f);
        float q = 0.f;
        for (int k = 0; k < 32; ++k) { const float d = y1s[(l << 5) + k] - mean; q += d * d; }
        const float var = q * (1.0f / 32.0f);
        stats[l] = mean;
        stats[8 + l] = rsqrtf(var + EPS);
    }
    __syncthreads();
    const float4 gg = ((const float4*)g1)[l];
    const float4 bb = ((const float4*)bt1)[l];
    const int g = l >> 3;
    const float mean = stats[g], inv = stats[8 + g];
    const float4 yv = ((const float4*)y1s)[l];
    float4 h;
    h.x = fmaxf((yv.x - mean) * inv * gg.x + bb.x, 0.f);
    h.y = fmaxf((yv.y - mean) * inv * gg.y + bb.y, 0.f);
    h.z = fmaxf((yv.z - mean) * inv * gg.z + bb.z, 0.f);
    h.w = fmaxf((yv.w - mean) * inv * gg.w + bb.w, 0.f);
    const float4 wv = ((const float4*)(W2 + c * 256))[l];
    float acc = wv.x * h.x + wv.y * h.y + wv.z * h.z + wv.w * h.w;
    acc += __shfl_down(acc, 32);
    acc += __shfl_down(acc, 16);
    acc += __shfl_down(acc, 8);
    acc += __shfl_down(acc, 4);
    acc += __shfl_down(acc, 2);
    acc += __shfl_down(acc, 1);
    if (l == 0) y2[c] = acc + b2[c];
}

// ---------------------------------------------------------------------------
// K5: h2 = relu(GN8(y2)*g2+bt2); out = h2 @ W3.T + b3. 1 x 128.
// ---------------------------------------------------------------------------
__global__ __launch_bounds__(128) void final_kernel(
    const float* __restrict__ y2,
    const float* __restrict__ g2, const float* __restrict__ bt2,
    const float* __restrict__ W3, const float* __restrict__ b3,
    float* __restrict__ out)
{
    __shared__ float y2s[128], h2[128];
    const int t = threadIdx.x;
    y2s[t] = y2[t];
    __syncthreads();
    {
        const int g = t >> 4;
        float s = 0.f;
        for (int k = 0; k < 16; ++k) s += y2s[(g << 4) + k];
        const float mean = s * (1.0f / 16.0f);
        float q = 0.f;
        for (int k = 0; k < 16; ++k) { const float d = y2s[(g << 4) + k] - mean; q += d * d; }
        const float var = q * (1.0f / 16.0f);
        const float xn = (y2s[t] - mean) * rsqrtf(var + EPS);
        h2[t] = fmaxf(xn * g2[t] + bt2[t], 0.f);
    }
    __syncthreads();
    const int wave = t >> 6, lane = t & 63;
    float acc = W3[wave * 128 + lane] * h2[lane]
              + W3[wave * 128 + 64 + lane] * h2[64 + lane];
    acc += __shfl_down(acc, 32);
    acc += __shfl_down(acc, 16);
    acc += __shfl_down(acc, 8);
    acc += __shfl_down(acc, 4);
    acc += __shfl_down(acc, 2);
    acc += __shfl_down(acc, 1);
    if (lane == 0) out[wave] = acc + b3[wave];
}

// ---------------------------------------------------------------------------
extern "C" void kernel_launch(void* const* d_in, const int* in_sizes, int n_in,
                              void* d_out, int out_size, void* d_ws, size_t ws_size,
                              hipStream_t stream)
{
    const float* points_c  = (const float*)d_in[0];
    const float* ref_feats = (const float*)d_in[1];
    const float* src_feats = (const float*)d_in[2];
    const float* trans     = (const float*)d_in[3];
    const float* W1  = (const float*)d_in[4];
    const float* b1  = (const float*)d_in[5];
    const float* g1  = (const float*)d_in[6];
    const float* bt1 = (const float*)d_in[7];
    const float* W2  = (const float*)d_in[8];
    const float* b2  = (const float*)d_in[9];
    const float* g2  = (const float*)d_in[10];
    const float* bt2 = (const float*)d_in[11];
    const float* W3  = (const float*)d_in[12];
    const float* b3  = (const float*)d_in[13];
    // d_in[14] = ref_length (int, == 128): fixed at compile time.

    // ws layout (floats):
    float* base     = (float*)d_ws;
    float* feat_mat = base;            // [0, 16384)
    float* rowF     = base + 16384;    // [16384, 16512)
    int*   rowFi    = (int*)(base + 16512);  // [16512, 16640)
    float* pts_ws   = base + 16640;    // [16640, 17664)
    float* geo      = base + 17664;    // [17664, 18176)  (16B aligned)
    float* y1       = base + 18176;    // [18176, 18432)  (16B aligned)
    float* y2       = base + 18432;    // [18432, 18560)

    feat_kernel<<<dim3(129), dim3(512), 0, stream>>>(
        ref_feats, src_feats, points_c, trans, feat_mat, rowF, rowFi, pts_ws);
    geo_kernel<<<dim3(1), dim3(1024), 0, stream>>>(pts_ws, feat_mat, rowF, rowFi, geo);
    mlp1_kernel<<<dim3(256), dim3(64), 0, stream>>>(geo, W1, b1, y1);
    mlp2_kernel<<<dim3(128), dim3(64), 0, stream>>>(y1, g1, bt1, W2, b2, y2);
    final_kernel<<<dim3(1), dim3(128), 0, stream>>>(y2, g2, bt2, W3, b3, (float*)d_out);
}